// Round 2
// baseline (385.934 us; speedup 1.0000x reference)
//
#include <hip/hip_runtime.h>
#include <hip/hip_bf16.h>

// PCILT conv2d: qdq(x,8b) conv qdq(W,8b), 3x3 s1 p1.
// Path: int8-valued bf16 MFMA (exact integer arithmetic), dequant in epilogue.
// Quantization of x is FUSED into the conv's A-staging (no big workspace).

typedef __attribute__((ext_vector_type(8))) short short8;   // 8 bf16 = 4 VGPRs (MFMA A/B frag)
typedef __attribute__((ext_vector_type(4))) float f32x4;    // MFMA C/D frag

#define N_IMG 16
#define C_IN 64
#define HW 112
#define O_CH 128
#define K_TOT 576         // 64*3*3

// ---------------- kernel 1: zero the scale slots ----------------
__global__ __launch_bounds__(64) void init_scal(unsigned* scal) {
    if (threadIdx.x < 2) scal[threadIdx.x] = 0u;
}

// ---------------- kernel 2: absmax of x and W -------------------
__global__ __launch_bounds__(256) void absmax_kernel(const float* __restrict__ x, int nx,
                                                     const float* __restrict__ w, int nw,
                                                     unsigned* __restrict__ scal) {
    float mx = 0.f, mw = 0.f;
    const int stride = gridDim.x * 256;
    for (int i = blockIdx.x * 256 + threadIdx.x; i < nx; i += stride)
        mx = fmaxf(mx, fabsf(x[i]));
    for (int i = blockIdx.x * 256 + threadIdx.x; i < nw; i += stride)
        mw = fmaxf(mw, fabsf(w[i]));
    #pragma unroll
    for (int off = 32; off > 0; off >>= 1) {
        mx = fmaxf(mx, __shfl_down(mx, off));
        mw = fmaxf(mw, __shfl_down(mw, off));
    }
    __shared__ float smx[4], smw[4];
    const int wave = threadIdx.x >> 6, lane = threadIdx.x & 63;
    if (lane == 0) { smx[wave] = mx; smw[wave] = mw; }
    __syncthreads();
    if (threadIdx.x == 0) {
        float a = fmaxf(fmaxf(smx[0], smx[1]), fmaxf(smx[2], smx[3]));
        float b = fmaxf(fmaxf(smw[0], smw[1]), fmaxf(smw[2], smw[3]));
        atomicMax(&scal[0], __float_as_uint(a));   // abs floats ordered as uints
        atomicMax(&scal[1], __float_as_uint(b));
    }
}

// -------- kernel 3: quantize W -> wt[o][(kh*3+kw)*64 + c] --------
__global__ __launch_bounds__(256) void quant_w(const float* __restrict__ w,
                                               const unsigned* __restrict__ scal,
                                               __hip_bfloat16* __restrict__ wt) {
    const int idx = blockIdx.x * 256 + threadIdx.x;
    if (idx >= O_CH * C_IN * 9) return;
    const float sw = fmaxf(__uint_as_float(scal[1]) * (1.f / 127.f), 1e-8f);
    const int kw = idx % 3;
    int t = idx / 3;
    const int kh = t % 3;
    t /= 3;
    const int c = t % C_IN;
    const int o = t / C_IN;
    float v = rintf(w[idx] / sw);
    v = fminf(fmaxf(v, -127.f), 127.f);
    wt[o * K_TOT + (kh * 3 + kw) * C_IN + c] = __float2bfloat16(v);
}

// ---------------- kernel 4: fused quant + implicit-GEMM conv ------------------
// One block per (n, oh): M-tile = 112 (one output row, 7 subtiles of 16),
// N-tile = 128 (all out channels), K loop = 18 steps of 32 (tap x c-half).
// 4 waves; wave w owns output channels [w*32, w*32+32).
#define LDSPITCH 40   // halves per LDS row (32 used + 8 pad -> 80B rows, 16B aligned)
__global__ __launch_bounds__(256) void conv_kernel(const float* __restrict__ x,
                                                   const __hip_bfloat16* __restrict__ wt,
                                                   const unsigned* __restrict__ scal,
                                                   float* __restrict__ out) {
    __shared__ __align__(16) unsigned short As[HW * LDSPITCH];    // [m=ow][k]  8960 B
    __shared__ __align__(16) unsigned short Bs[O_CH * LDSPITCH];  // [n=o ][k] 10240 B

    const int tid = threadIdx.x;
    const int wave = tid >> 6, lane = tid & 63;
    const int quad = lane >> 4, l16 = lane & 15;
    const int n = blockIdx.x / HW, oh = blockIdx.x % HW;

    const float sx = fmaxf(__uint_as_float(scal[0]) * (1.f / 127.f), 1e-8f);
    const float inv_sx = 1.f / sx;

    f32x4 acc[7][2];
    #pragma unroll
    for (int mt = 0; mt < 7; ++mt) {
        acc[mt][0] = (f32x4)0.f;
        acc[mt][1] = (f32x4)0.f;
    }

    const unsigned short* wtp = (const unsigned short*)wt;

    for (int step = 0; step < 18; ++step) {
        const int tap = step >> 1, h = step & 1;
        const int kh = tap / 3, kw = tap % 3;
        const int cbase = h * 32;
        const int ih = oh + kh - 1;                    // wave-uniform per step
        const bool rowok = ((unsigned)ih < (unsigned)HW);
        const long abase = ((long)(n * C_IN + cbase) * HW + (rowok ? ih : 0)) * HW + (kw - 1);
        __syncthreads();
        // ---- stage A tile: As[ow][c] = qdq(x[n][cbase+c][ih][ow+kw-1]), 112x32
        #pragma unroll
        for (int i = 0; i < 14; ++i) {
            const int l = tid + 256 * i;       // 3584 = 14*256 exact
            const int c = l / HW;              // 0..31
            const int ow = l - c * HW;         // 0..111 (lanes -> consecutive addrs)
            const int iw = ow + kw - 1;
            const bool ok = rowok && ((unsigned)iw < (unsigned)HW);
            float xv = 0.f;
            if (ok) xv = x[abase + (long)c * (HW * HW) + ow];
            float v = fminf(fmaxf(rintf(xv * inv_sx), -127.f), 127.f);
            const __hip_bfloat16 b = __float2bfloat16(v);
            As[ow * LDSPITCH + c] = *(const unsigned short*)&b;
        }
        // ---- stage B tile: Bs[o][k] = wt[o][step*32 + k], 128x32 (vectorized)
        {
            const int o = tid >> 1, part = tid & 1;
            const f32x4* src = (const f32x4*)(wtp + o * K_TOT + step * 32);
            f32x4* dst = (f32x4*)(Bs + o * LDSPITCH + part * 16);
            dst[0] = src[part * 2 + 0];
            dst[1] = src[part * 2 + 1];
        }
        __syncthreads();
        // ---- fragments + MFMA
        short8 bfr[2];
        #pragma unroll
        for (int ot = 0; ot < 2; ++ot) {
            const int row = wave * 32 + ot * 16 + l16;
            bfr[ot] = *(const short8*)(Bs + row * LDSPITCH + quad * 8);
        }
        #pragma unroll
        for (int mt = 0; mt < 7; ++mt) {
            const short8 afr = *(const short8*)(As + (mt * 16 + l16) * LDSPITCH + quad * 8);
            acc[mt][0] = __builtin_amdgcn_mfma_f32_16x16x32_bf16(afr, bfr[0], acc[mt][0], 0, 0, 0);
            acc[mt][1] = __builtin_amdgcn_mfma_f32_16x16x32_bf16(afr, bfr[1], acc[mt][1], 0, 0, 0);
        }
    }

    // ---- epilogue: dequant and store (4 consecutive ow per lane -> float4)
    const float aw = __uint_as_float(scal[1]);
    const float s = sx * fmaxf(aw * (1.f / 127.f), 1e-8f);
    #pragma unroll
    for (int mt = 0; mt < 7; ++mt) {
        #pragma unroll
        for (int ot = 0; ot < 2; ++ot) {
            const int o = wave * 32 + ot * 16 + l16;         // D col = lane&15
            const int mrow = mt * 16 + quad * 4;             // D row = quad*4 + reg
            const f32x4 v = acc[mt][ot] * s;
            *(f32x4*)(out + (((long)(n * O_CH + o) * HW + oh) * HW + mrow)) = v;
        }
    }
}

extern "C" void kernel_launch(void* const* d_in, const int* in_sizes, int n_in,
                              void* d_out, int out_size, void* d_ws, size_t ws_size,
                              hipStream_t stream) {
    const float* x = (const float*)d_in[0];
    const float* W = (const float*)d_in[1];
    float* out = (float*)d_out;

    unsigned* scal = (unsigned*)d_ws;                               // 8 B
    __hip_bfloat16* wt = (__hip_bfloat16*)((char*)d_ws + 1024);     // 147,456 B

    const int nx = N_IMG * C_IN * HW * HW;   // 12,845,056
    const int nw = O_CH * C_IN * 9;          // 73,728

    hipLaunchKernelGGL(init_scal, dim3(1), dim3(64), 0, stream, scal);
    hipLaunchKernelGGL(absmax_kernel, dim3(1024), dim3(256), 0, stream, x, nx, W, nw, scal);
    hipLaunchKernelGGL(quant_w, dim3(288), dim3(256), 0, stream, W, scal, wt);
    hipLaunchKernelGGL(conv_kernel, dim3(N_IMG * HW), dim3(256), 0, stream, x, wt, scal, out);
}

// Round 3
// 302.121 us; speedup vs baseline: 1.2774x; 1.2774x over previous
//
#include <hip/hip_runtime.h>
#include <hip/hip_bf16.h>

// PCILT conv2d: qdq(x,8b) conv qdq(W,8b), 3x3 s1 p1.
// Path: pre-quantize x -> NHWC bf16 (integer-valued), W -> [o][tap*64+c] bf16;
// conv = barrier-free implicit GEMM, MFMA fragments loaded DIRECTLY from
// global (16B/lane, L1/L2-resident). Dequant in epilogue. Exact-integer math.

typedef __attribute__((ext_vector_type(8))) short short8;   // 8 bf16 (MFMA A/B frag)
typedef __attribute__((ext_vector_type(4))) float f32x4;    // MFMA C/D frag
typedef __attribute__((ext_vector_type(4))) float float4v;

#define N_IMG 16
#define C_IN 64
#define HW 112
#define O_CH 128
#define K_TOT 576         // 64*3*3

// ---------------- kernel 1: zero the scale slots ----------------
__global__ __launch_bounds__(64) void init_scal(unsigned* scal) {
    if (threadIdx.x < 2) scal[threadIdx.x] = 0u;
}

// ---------------- kernel 2: absmax of x and W -------------------
__global__ __launch_bounds__(256) void absmax_kernel(const float* __restrict__ x, int nx4,
                                                     const float* __restrict__ w, int nw,
                                                     unsigned* __restrict__ scal) {
    float mx = 0.f, mw = 0.f;
    const int stride = gridDim.x * 256;
    const float4v* x4 = (const float4v*)x;
    for (int i = blockIdx.x * 256 + threadIdx.x; i < nx4; i += stride) {
        const float4v v = x4[i];
        mx = fmaxf(mx, fmaxf(fmaxf(fabsf(v.x), fabsf(v.y)), fmaxf(fabsf(v.z), fabsf(v.w))));
    }
    for (int i = blockIdx.x * 256 + threadIdx.x; i < nw; i += stride)
        mw = fmaxf(mw, fabsf(w[i]));
    #pragma unroll
    for (int off = 32; off > 0; off >>= 1) {
        mx = fmaxf(mx, __shfl_down(mx, off));
        mw = fmaxf(mw, __shfl_down(mw, off));
    }
    __shared__ float smx[4], smw[4];
    const int wave = threadIdx.x >> 6, lane = threadIdx.x & 63;
    if (lane == 0) { smx[wave] = mx; smw[wave] = mw; }
    __syncthreads();
    if (threadIdx.x == 0) {
        float a = fmaxf(fmaxf(smx[0], smx[1]), fmaxf(smx[2], smx[3]));
        float b = fmaxf(fmaxf(smw[0], smw[1]), fmaxf(smw[2], smw[3]));
        atomicMax(&scal[0], __float_as_uint(a));   // abs floats ordered as uints
        atomicMax(&scal[1], __float_as_uint(b));
    }
}

// -------- kernel 3: quantize W -> wt[o][(kh*3+kw)*64 + c] --------
__global__ __launch_bounds__(256) void quant_w(const float* __restrict__ w,
                                               const unsigned* __restrict__ scal,
                                               __hip_bfloat16* __restrict__ wt) {
    const int idx = blockIdx.x * 256 + threadIdx.x;
    if (idx >= O_CH * C_IN * 9) return;
    const float sw = fmaxf(__uint_as_float(scal[1]) * (1.f / 127.f), 1e-8f);
    const int kw = idx % 3;
    int t = idx / 3;
    const int kh = t % 3;
    t /= 3;
    const int c = t % C_IN;
    const int o = t / C_IN;
    float v = rintf(w[idx] / sw);
    v = fminf(fmaxf(v, -127.f), 127.f);
    wt[o * K_TOT + (kh * 3 + kw) * C_IN + c] = __float2bfloat16(v);
}

// -------- kernel 4: quantize+transpose x -> xq NHWC bf16 --------
// One block per (n,h): 64c x 112w tile, LDS transpose, coalesced both sides.
#define TP 70   // LDS pitch in halves (word-stride 35: odd -> conflict-free writes)
__global__ __launch_bounds__(256) void quant_x(const float* __restrict__ x,
                                               const unsigned* __restrict__ scal,
                                               unsigned short* __restrict__ xq) {
    __shared__ unsigned short tile[HW * TP];   // 15,680 B
    const int tid = threadIdx.x;
    const int n = blockIdx.x / HW, h = blockIdx.x % HW;
    const float inv_sx = 1.f / fmaxf(__uint_as_float(scal[0]) * (1.f / 127.f), 1e-8f);
    // read 64c x 112w coalesced along w, quantize, LDS[w][c]
    #pragma unroll
    for (int i = 0; i < 28; ++i) {                 // 28*256 = 7168 = 64*112
        const int l = i * 256 + tid;
        const int c = l / HW;
        const int w = l - c * HW;
        const float xv = x[((long)(n * C_IN + c) * HW + h) * HW + w];
        const float v = fminf(fmaxf(rintf(xv * inv_sx), -127.f), 127.f);
        const __hip_bfloat16 b = __float2bfloat16(v);
        tile[w * TP + c] = *(const unsigned short*)&b;
    }
    __syncthreads();
    // write coalesced along c (ushort2 per lane)
    const int cg = tid & 31, wi = tid >> 5;        // cg: c-pair, wi: 0..7
    unsigned short* dst = xq + ((long)(n * HW + h) * HW) * C_IN;
    #pragma unroll
    for (int j = 0; j < 14; ++j) {
        const int w = j * 8 + wi;
        *(ushort2*)(dst + w * C_IN + cg * 2) = *(const ushort2*)(tile + w * TP + cg * 2);
    }
}

// ---------------- kernel 5: barrier-free implicit-GEMM conv ------------------
// One block per (n, oh). 4 waves: wave w owns out channels [w*32, w*32+32).
// M-tile = 112 (7x16), K = 18 half-steps of 32 c. Fragments loaded straight
// from global (xq NHWC, wt) — no LDS, no __syncthreads.
__global__ __launch_bounds__(256) void conv_kernel(const unsigned short* __restrict__ xq,
                                                   const unsigned short* __restrict__ wtp,
                                                   const unsigned* __restrict__ scal,
                                                   float* __restrict__ out) {
    const int tid = threadIdx.x;
    const int wave = tid >> 6, lane = tid & 63;
    const int quad = lane >> 4, l16 = lane & 15;
    // XCD swizzle: blocks resident on one XCD get consecutive (n,oh) -> L2 row reuse
    const int lin = (blockIdx.x & 7) * 224 + (blockIdx.x >> 3);
    const int n = lin / HW, oh = lin % HW;

    f32x4 acc[7][2];
    #pragma unroll
    for (int mt = 0; mt < 7; ++mt) { acc[mt][0] = (f32x4)0.f; acc[mt][1] = (f32x4)0.f; }

    const int lofs = l16 * C_IN + quad * 8;        // per-lane A offset within a row
    const unsigned short* wbase = wtp + (wave * 32 + l16) * K_TOT + quad * 8;

    #pragma unroll
    for (int kh = 0; kh < 3; ++kh) {
        const int ih = oh + kh - 1;
        if ((unsigned)ih >= (unsigned)HW) continue;          // uniform skip
        const unsigned short* xr = xq + ((long)(n * HW + ih) * HW) * C_IN;
        #pragma unroll
        for (int kw = 0; kw < 3; ++kw) {
            const int tap = kh * 3 + kw;
            const unsigned short* xt = xr + (kw - 1) * C_IN + lofs;
            #pragma unroll
            for (int half = 0; half < 2; ++half) {
                short8 bfr[2];
                #pragma unroll
                for (int ot = 0; ot < 2; ++ot)
                    bfr[ot] = *(const short8*)(wbase + ot * 16 * K_TOT + tap * C_IN + half * 32);
                short8 afr[7];
                #pragma unroll
                for (int mt = 0; mt < 7; ++mt) {
                    const int iw = mt * 16 + l16 + kw - 1;
                    short8 a = (short8)0;
                    if ((unsigned)iw < (unsigned)HW)
                        a = *(const short8*)(xt + mt * 16 * C_IN + half * 32);
                    afr[mt] = a;
                }
                #pragma unroll
                for (int mt = 0; mt < 7; ++mt) {
                    acc[mt][0] = __builtin_amdgcn_mfma_f32_16x16x32_bf16(afr[mt], bfr[0], acc[mt][0], 0, 0, 0);
                    acc[mt][1] = __builtin_amdgcn_mfma_f32_16x16x32_bf16(afr[mt], bfr[1], acc[mt][1], 0, 0, 0);
                }
            }
        }
    }

    // ---- epilogue: dequant and store (4 consecutive ow per lane -> float4)
    const float s = fmaxf(__uint_as_float(scal[0]) * (1.f / 127.f), 1e-8f) *
                    fmaxf(__uint_as_float(scal[1]) * (1.f / 127.f), 1e-8f);
    #pragma unroll
    for (int mt = 0; mt < 7; ++mt) {
        #pragma unroll
        for (int ot = 0; ot < 2; ++ot) {
            const int o = wave * 32 + ot * 16 + l16;         // D col = lane&15
            const int mrow = mt * 16 + quad * 4;             // D row = quad*4 + reg
            const f32x4 v = acc[mt][ot] * s;
            *(f32x4*)(out + (((long)(n * O_CH + o) * HW + oh) * HW + mrow)) = v;
        }
    }
}

extern "C" void kernel_launch(void* const* d_in, const int* in_sizes, int n_in,
                              void* d_out, int out_size, void* d_ws, size_t ws_size,
                              hipStream_t stream) {
    const float* x = (const float*)d_in[0];
    const float* W = (const float*)d_in[1];
    float* out = (float*)d_out;

    unsigned* scal = (unsigned*)d_ws;                                    // 8 B
    __hip_bfloat16* wt = (__hip_bfloat16*)((char*)d_ws + 1024);          // 147,456 B
    unsigned short* xq = (unsigned short*)((char*)d_ws + 148480);        // 25,690,112 B

    const int nx = N_IMG * C_IN * HW * HW;   // 12,845,056 (divisible by 4)
    const int nw = O_CH * C_IN * 9;          // 73,728

    hipLaunchKernelGGL(init_scal, dim3(1), dim3(64), 0, stream, scal);
    hipLaunchKernelGGL(absmax_kernel, dim3(1024), dim3(256), 0, stream, x, nx / 4, W, nw, scal);
    hipLaunchKernelGGL(quant_w, dim3(288), dim3(256), 0, stream, W, scal, wt);
    hipLaunchKernelGGL(quant_x, dim3(N_IMG * HW), dim3(256), 0, stream, x, scal, (unsigned short*)xq);
    hipLaunchKernelGGL(conv_kernel, dim3(N_IMG * HW), dim3(256), 0, stream,
                       (const unsigned short*)xq, (const unsigned short*)wt, scal, out);
}

// Round 4
// 238.641 us; speedup vs baseline: 1.6172x; 1.2660x over previous
//
#include <hip/hip_runtime.h>
#include <hip/hip_bf16.h>

// PCILT conv2d: qdq(x,8b) conv qdq(W,8b), 3x3 s1 p1.
// Path: pre-quantize x -> NHWC bf16 (integer-valued), W -> [o][tap*64+c] bf16.
// Conv: one block per (n,oh); stage 3 padded xq rows to LDS ONCE (one barrier),
// K-loop = 9 taps x 2 c-halves of pure ds_read_b128 + MFMA, B-fragments
// prefetched one tap ahead from global (L2-resident). Exact-integer math.

typedef __attribute__((ext_vector_type(8))) short short8;   // 8 bf16 (MFMA A/B frag)
typedef __attribute__((ext_vector_type(4))) float f32x4;    // MFMA C/D frag
typedef __attribute__((ext_vector_type(4))) float float4v;

#define N_IMG 16
#define C_IN 64
#define HW 112
#define O_CH 128
#define K_TOT 576         // 64*3*3
#define TPITCH 72         // LDS halves per ow-row (pad 64 -> 72: min bank aliasing)

// ---------------- kernel 1: zero the scale slots ----------------
__global__ __launch_bounds__(64) void init_scal(unsigned* scal) {
    if (threadIdx.x < 2) scal[threadIdx.x] = 0u;
}

// ---------------- kernel 2: absmax of x and W -------------------
__global__ __launch_bounds__(256) void absmax_kernel(const float* __restrict__ x, int nx4,
                                                     const float* __restrict__ w, int nw,
                                                     unsigned* __restrict__ scal) {
    float mx = 0.f, mw = 0.f;
    const int stride = gridDim.x * 256;
    const float4v* x4 = (const float4v*)x;
    for (int i = blockIdx.x * 256 + threadIdx.x; i < nx4; i += stride) {
        const float4v v = x4[i];
        mx = fmaxf(mx, fmaxf(fmaxf(fabsf(v.x), fabsf(v.y)), fmaxf(fabsf(v.z), fabsf(v.w))));
    }
    for (int i = blockIdx.x * 256 + threadIdx.x; i < nw; i += stride)
        mw = fmaxf(mw, fabsf(w[i]));
    #pragma unroll
    for (int off = 32; off > 0; off >>= 1) {
        mx = fmaxf(mx, __shfl_down(mx, off));
        mw = fmaxf(mw, __shfl_down(mw, off));
    }
    __shared__ float smx[4], smw[4];
    const int wave = threadIdx.x >> 6, lane = threadIdx.x & 63;
    if (lane == 0) { smx[wave] = mx; smw[wave] = mw; }
    __syncthreads();
    if (threadIdx.x == 0) {
        float a = fmaxf(fmaxf(smx[0], smx[1]), fmaxf(smx[2], smx[3]));
        float b = fmaxf(fmaxf(smw[0], smw[1]), fmaxf(smw[2], smw[3]));
        atomicMax(&scal[0], __float_as_uint(a));   // abs floats ordered as uints
        atomicMax(&scal[1], __float_as_uint(b));
    }
}

// -------- kernel 3: quantize W -> wt[o][(kh*3+kw)*64 + c] --------
__global__ __launch_bounds__(256) void quant_w(const float* __restrict__ w,
                                               const unsigned* __restrict__ scal,
                                               __hip_bfloat16* __restrict__ wt) {
    const int idx = blockIdx.x * 256 + threadIdx.x;
    if (idx >= O_CH * C_IN * 9) return;
    const float sw = fmaxf(__uint_as_float(scal[1]) * (1.f / 127.f), 1e-8f);
    const int kw = idx % 3;
    int t = idx / 3;
    const int kh = t % 3;
    t /= 3;
    const int c = t % C_IN;
    const int o = t / C_IN;
    float v = rintf(w[idx] / sw);
    v = fminf(fmaxf(v, -127.f), 127.f);
    wt[o * K_TOT + (kh * 3 + kw) * C_IN + c] = __float2bfloat16(v);
}

// -------- kernel 4: quantize+transpose x -> xq NHWC bf16 --------
// One block per (n,h); float4 reads along w, LDS transpose, ushort8 writes along c.
__global__ __launch_bounds__(256) void quant_x(const float* __restrict__ x,
                                               const unsigned* __restrict__ scal,
                                               unsigned short* __restrict__ xq) {
    __shared__ __align__(16) unsigned short tile[HW * TPITCH];   // [w][c] 16,128 B
    const int tid = threadIdx.x;
    const int n = blockIdx.x / HW, h = blockIdx.x % HW;
    const float inv_sx = 1.f / fmaxf(__uint_as_float(scal[0]) * (1.f / 127.f), 1e-8f);
    #pragma unroll
    for (int i = 0; i < 7; ++i) {                   // 7*256 = 1792 = 64c * 28 w-quads
        const int l = i * 256 + tid;
        const int c = l / 28, w4 = l - c * 28;
        const float4v v = *(const float4v*)(x + ((long)(n * C_IN + c) * HW + h) * HW + w4 * 4);
        const float q0 = fminf(fmaxf(rintf(v.x * inv_sx), -127.f), 127.f);
        const float q1 = fminf(fmaxf(rintf(v.y * inv_sx), -127.f), 127.f);
        const float q2 = fminf(fmaxf(rintf(v.z * inv_sx), -127.f), 127.f);
        const float q3 = fminf(fmaxf(rintf(v.w * inv_sx), -127.f), 127.f);
        const __hip_bfloat16 b0 = __float2bfloat16(q0), b1 = __float2bfloat16(q1);
        const __hip_bfloat16 b2 = __float2bfloat16(q2), b3 = __float2bfloat16(q3);
        tile[(w4 * 4 + 0) * TPITCH + c] = *(const unsigned short*)&b0;
        tile[(w4 * 4 + 1) * TPITCH + c] = *(const unsigned short*)&b1;
        tile[(w4 * 4 + 2) * TPITCH + c] = *(const unsigned short*)&b2;
        tile[(w4 * 4 + 3) * TPITCH + c] = *(const unsigned short*)&b3;
    }
    __syncthreads();
    const int cw = tid & 7, wi = tid >> 3;          // 8 c-octets x 32 w-slots
    unsigned short* dst = xq + ((long)(n * HW + h) * HW) * C_IN;
    #pragma unroll
    for (int j = 0; j < 4; ++j) {
        const int w = j * 32 + wi;
        if (w < HW)
            *(short8*)(dst + w * C_IN + cw * 8) = *(const short8*)(tile + w * TPITCH + cw * 8);
    }
}

// ---------------- kernel 5: conv — static-LDS A, pipelined B ------------------
__global__ __launch_bounds__(256) void conv_kernel(const unsigned short* __restrict__ xq,
                                                   const unsigned short* __restrict__ wtp,
                                                   const unsigned* __restrict__ scal,
                                                   float* __restrict__ out) {
    __shared__ __align__(16) unsigned short xs[3 * 114 * TPITCH];   // 49,248 B
    const int tid = threadIdx.x;
    const int wave = tid >> 6, lane = tid & 63;
    const int quad = lane >> 4, l16 = lane & 15;
    // XCD swizzle: consecutive-resident blocks get consecutive (n,oh)
    const int lin = (blockIdx.x & 7) * 224 + (blockIdx.x >> 3);
    const int n = lin / HW, oh = lin % HW;

    // ---- stage: zero border columns (ow_lds = 0, 113) ----
    if (tid < 48) {
        const int r = tid >> 4, col = (tid >> 3) & 1, c8 = tid & 7;
        *(short8*)(xs + (r * 114 + col * 113) * TPITCH + c8 * 8) = (short8)0;
    }
    // ---- stage 3 rows (ih = oh-1 .. oh+1), 16B chunks, coalesced ----
    #pragma unroll
    for (int it = 0; it < 11; ++it) {
        const int g = it * 256 + tid;               // 2688 = 3 rows * 112 ow * 8 c8
        if (g < 2688) {
            const int r = g / 896, rem = g - r * 896;
            const int ow = rem >> 3, c8 = rem & 7;
            const int ih = oh - 1 + r;
            short8 v = (short8)0;
            if ((unsigned)ih < (unsigned)HW)
                v = *(const short8*)(xq + (((long)(n * HW + ih) * HW + ow) * C_IN) + c8 * 8);
            *(short8*)(xs + (r * 114 + ow + 1) * TPITCH + c8 * 8) = v;
        }
    }

    f32x4 acc[7][2];
    #pragma unroll
    for (int mt = 0; mt < 7; ++mt) { acc[mt][0] = (f32x4)0.f; acc[mt][1] = (f32x4)0.f; }

    // B-fragment pointers: wave owns channels [wave*32, wave*32+32)
    const unsigned short* wrow0 = wtp + (wave * 32 + l16) * K_TOT + quad * 8;
    const unsigned short* wrow1 = wrow0 + 16 * K_TOT;

    short8 bcur[2][2], bnxt[2][2];
    #pragma unroll
    for (int half = 0; half < 2; ++half) {
        bcur[half][0] = *(const short8*)(wrow0 + half * 32);
        bcur[half][1] = *(const short8*)(wrow1 + half * 32);
    }

    __syncthreads();

    #pragma unroll
    for (int tap = 0; tap < 9; ++tap) {
        if (tap < 8) {                              // prefetch next tap's B frags
            #pragma unroll
            for (int half = 0; half < 2; ++half) {
                bnxt[half][0] = *(const short8*)(wrow0 + (tap + 1) * C_IN + half * 32);
                bnxt[half][1] = *(const short8*)(wrow1 + (tap + 1) * C_IN + half * 32);
            }
        }
        const unsigned short* rowb = xs + (tap / 3) * (114 * TPITCH) + (tap % 3) * TPITCH + l16 * TPITCH + quad * 8;
        #pragma unroll
        for (int half = 0; half < 2; ++half) {
            #pragma unroll
            for (int mt = 0; mt < 7; ++mt) {
                const short8 afr = *(const short8*)(rowb + mt * (16 * TPITCH) + half * 32);
                acc[mt][0] = __builtin_amdgcn_mfma_f32_16x16x32_bf16(afr, bcur[half][0], acc[mt][0], 0, 0, 0);
                acc[mt][1] = __builtin_amdgcn_mfma_f32_16x16x32_bf16(afr, bcur[half][1], acc[mt][1], 0, 0, 0);
            }
        }
        #pragma unroll
        for (int half = 0; half < 2; ++half) {
            bcur[half][0] = bnxt[half][0];
            bcur[half][1] = bnxt[half][1];
        }
    }

    // ---- epilogue: dequant and store (4 consecutive ow per lane -> float4)
    const float s = fmaxf(__uint_as_float(scal[0]) * (1.f / 127.f), 1e-8f) *
                    fmaxf(__uint_as_float(scal[1]) * (1.f / 127.f), 1e-8f);
    #pragma unroll
    for (int mt = 0; mt < 7; ++mt) {
        #pragma unroll
        for (int ot = 0; ot < 2; ++ot) {
            const int o = wave * 32 + ot * 16 + l16;         // D col = lane&15
            const int mrow = mt * 16 + quad * 4;             // D row = quad*4 + reg
            const f32x4 v = acc[mt][ot] * s;
            *(f32x4*)(out + (((long)(n * O_CH + o) * HW + oh) * HW + mrow)) = v;
        }
    }
}

extern "C" void kernel_launch(void* const* d_in, const int* in_sizes, int n_in,
                              void* d_out, int out_size, void* d_ws, size_t ws_size,
                              hipStream_t stream) {
    const float* x = (const float*)d_in[0];
    const float* W = (const float*)d_in[1];
    float* out = (float*)d_out;

    unsigned* scal = (unsigned*)d_ws;                                    // 8 B
    __hip_bfloat16* wt = (__hip_bfloat16*)((char*)d_ws + 1024);          // 147,456 B
    unsigned short* xq = (unsigned short*)((char*)d_ws + 148480);        // 25,690,112 B

    const int nx = N_IMG * C_IN * HW * HW;   // 12,845,056 (divisible by 4)
    const int nw = O_CH * C_IN * 9;          // 73,728

    hipLaunchKernelGGL(init_scal, dim3(1), dim3(64), 0, stream, scal);
    hipLaunchKernelGGL(absmax_kernel, dim3(2048), dim3(256), 0, stream, x, nx / 4, W, nw, scal);
    hipLaunchKernelGGL(quant_w, dim3(288), dim3(256), 0, stream, W, scal, wt);
    hipLaunchKernelGGL(quant_x, dim3(N_IMG * HW), dim3(256), 0, stream, x, scal, xq);
    hipLaunchKernelGGL(conv_kernel, dim3(N_IMG * HW), dim3(256), 0, stream, xq, (const unsigned short*)wt, scal, out);
}

// Round 5
// 198.762 us; speedup vs baseline: 1.9417x; 1.2006x over previous
//
#include <hip/hip_runtime.h>
#include <hip/hip_bf16.h>

// PCILT conv2d: qdq(x,8b) conv qdq(W,8b), 3x3 s1 p1.
// Path: pre-quantize x -> NHWC bf16 (integer-valued), W -> [o][tap*64+c] bf16.
// Conv: one block per (n,oh); stage 3 padded xq rows to LDS ONCE (one barrier),
// K-loop = 9 taps x 2 c-halves of pure ds_read_b128 + MFMA, B-fragments
// prefetched one tap ahead from global (L2-resident). Exact-integer math.
// Scales via atomic-free two-phase absmax reduction (partials aliased in ws).

typedef __attribute__((ext_vector_type(8))) short short8;   // 8 bf16 (MFMA A/B frag)
typedef __attribute__((ext_vector_type(4))) float f32x4;    // MFMA C/D frag
typedef __attribute__((ext_vector_type(4))) float float4v;

#define N_IMG 16
#define C_IN 64
#define HW 112
#define O_CH 128
#define K_TOT 576         // 64*3*3
#define TPITCH 72         // LDS halves per ow-row (64 + 8 pad)
#define NPART 3136        // absmax partial blocks (3136*256*4 float4 == nx4)

// ---------------- kernel 1: per-block absmax partials (NO atomics) ----------
// part[b] = max|x| over block b's 4096 floats; part[NPART+b] = max|W| slice.
__global__ __launch_bounds__(256) void absmax_part(const float* __restrict__ x,
                                                   const float* __restrict__ w,
                                                   float* __restrict__ part) {
    const int b = blockIdx.x, tid = threadIdx.x;
    const float4v* x4 = (const float4v*)x;
    const long base = (long)b * 1024 + tid;
    // 4 independent 16B loads per thread (pipelined, coalesced)
    const float4v v0 = x4[base];
    const float4v v1 = x4[base + 256];
    const float4v v2 = x4[base + 512];
    const float4v v3 = x4[base + 768];
    float mx = fmaxf(fmaxf(fmaxf(fabsf(v0.x), fabsf(v0.y)), fmaxf(fabsf(v0.z), fabsf(v0.w))),
                     fmaxf(fmaxf(fabsf(v1.x), fabsf(v1.y)), fmaxf(fabsf(v1.z), fabsf(v1.w))));
    mx = fmaxf(mx, fmaxf(fmaxf(fabsf(v2.x), fabsf(v2.y)), fmaxf(fabsf(v2.z), fabsf(v2.w))));
    mx = fmaxf(mx, fmaxf(fmaxf(fabsf(v3.x), fabsf(v3.y)), fmaxf(fabsf(v3.z), fabsf(v3.w))));
    float mw = 0.f;
    if (b < 72) {   // 72*256 float4 == 73,728 W floats exactly
        const float4v q = ((const float4v*)w)[b * 256 + tid];
        mw = fmaxf(fmaxf(fabsf(q.x), fabsf(q.y)), fmaxf(fabsf(q.z), fabsf(q.w)));
    }
    #pragma unroll
    for (int off = 32; off > 0; off >>= 1) {
        mx = fmaxf(mx, __shfl_down(mx, off));
        mw = fmaxf(mw, __shfl_down(mw, off));
    }
    __shared__ float smx[4], smw[4];
    const int wave = tid >> 6, lane = tid & 63;
    if (lane == 0) { smx[wave] = mx; smw[wave] = mw; }
    __syncthreads();
    if (tid == 0) {
        part[b]         = fmaxf(fmaxf(smx[0], smx[1]), fmaxf(smx[2], smx[3]));
        part[NPART + b] = fmaxf(fmaxf(smw[0], smw[1]), fmaxf(smw[2], smw[3]));
    }
}

// ---------------- kernel 2: fold partials -> scal[0]=|x|max, scal[1]=|W|max --
__global__ __launch_bounds__(256) void reduce_scal(const float* __restrict__ part,
                                                   unsigned* __restrict__ scal) {
    const int tid = threadIdx.x;
    float mx = 0.f, mw = 0.f;
    for (int i = tid; i < NPART; i += 256) {
        mx = fmaxf(mx, part[i]);
        mw = fmaxf(mw, part[NPART + i]);
    }
    #pragma unroll
    for (int off = 32; off > 0; off >>= 1) {
        mx = fmaxf(mx, __shfl_down(mx, off));
        mw = fmaxf(mw, __shfl_down(mw, off));
    }
    __shared__ float smx[4], smw[4];
    const int wave = tid >> 6, lane = tid & 63;
    if (lane == 0) { smx[wave] = mx; smw[wave] = mw; }
    __syncthreads();
    if (tid == 0) {
        scal[0] = __float_as_uint(fmaxf(fmaxf(smx[0], smx[1]), fmaxf(smx[2], smx[3])));
        scal[1] = __float_as_uint(fmaxf(fmaxf(smw[0], smw[1]), fmaxf(smw[2], smw[3])));
    }
}

// -------- kernel 3: quantize W -> wt[o][(kh*3+kw)*64 + c] --------
__global__ __launch_bounds__(256) void quant_w(const float* __restrict__ w,
                                               const unsigned* __restrict__ scal,
                                               __hip_bfloat16* __restrict__ wt) {
    const int idx = blockIdx.x * 256 + threadIdx.x;
    if (idx >= O_CH * C_IN * 9) return;
    const float sw = fmaxf(__uint_as_float(scal[1]) * (1.f / 127.f), 1e-8f);
    const int kw = idx % 3;
    int t = idx / 3;
    const int kh = t % 3;
    t /= 3;
    const int c = t % C_IN;
    const int o = t / C_IN;
    float v = rintf(w[idx] / sw);
    v = fminf(fmaxf(v, -127.f), 127.f);
    wt[o * K_TOT + (kh * 3 + kw) * C_IN + c] = __float2bfloat16(v);
}

// -------- kernel 4: quantize+transpose x -> xq NHWC bf16 --------
// One block per (n,h); float4 reads along w, LDS transpose (XOR-swizzled
// c-octets: write conflicts 14-way -> ~4-way), ushort8 writes along c.
__global__ __launch_bounds__(256) void quant_x(const float* __restrict__ x,
                                               const unsigned* __restrict__ scal,
                                               unsigned short* __restrict__ xq) {
    __shared__ __align__(16) unsigned short tile[HW * TPITCH];   // [w][c-swizzled] 16,128 B
    const int tid = threadIdx.x;
    const int n = blockIdx.x / HW, h = blockIdx.x % HW;
    const float inv_sx = 1.f / fmaxf(__uint_as_float(scal[0]) * (1.f / 127.f), 1e-8f);
    #pragma unroll
    for (int i = 0; i < 7; ++i) {                   // 7*256 = 1792 = 64c * 28 w-quads
        const int l = i * 256 + tid;
        const int c = l / 28, w4 = l - c * 28;
        const float4v v = *(const float4v*)(x + ((long)(n * C_IN + c) * HW + h) * HW + w4 * 4);
        float q[4];
        q[0] = fminf(fmaxf(rintf(v.x * inv_sx), -127.f), 127.f);
        q[1] = fminf(fmaxf(rintf(v.y * inv_sx), -127.f), 127.f);
        q[2] = fminf(fmaxf(rintf(v.z * inv_sx), -127.f), 127.f);
        q[3] = fminf(fmaxf(rintf(v.w * inv_sx), -127.f), 127.f);
        const int osw = ((c >> 3) ^ (w4 & 7)) * 8 + (c & 7);   // swizzled c position
        #pragma unroll
        for (int j = 0; j < 4; ++j) {
            const __hip_bfloat16 b = __float2bfloat16(q[j]);
            tile[(w4 * 4 + j) * TPITCH + osw] = *(const unsigned short*)&b;
        }
    }
    __syncthreads();
    const int cw = tid & 7, wi = tid >> 3;          // 8 c-octets x 32 w-slots
    unsigned short* dst = xq + ((long)(n * HW + h) * HW) * C_IN;
    #pragma unroll
    for (int j = 0; j < 4; ++j) {
        const int w = j * 32 + wi;
        if (w < HW) {
            const int osrc = (cw ^ ((w >> 2) & 7)) * 8;        // undo swizzle
            *(short8*)(dst + w * C_IN + cw * 8) = *(const short8*)(tile + w * TPITCH + osrc);
        }
    }
}

// ---------------- kernel 5: conv — static-LDS A, pipelined B ------------------
__global__ __launch_bounds__(256) void conv_kernel(const unsigned short* __restrict__ xq,
                                                   const unsigned short* __restrict__ wtp,
                                                   const unsigned* __restrict__ scal,
                                                   float* __restrict__ out) {
    __shared__ __align__(16) unsigned short xs[3 * 114 * TPITCH];   // 49,248 B
    const int tid = threadIdx.x;
    const int wave = tid >> 6, lane = tid & 63;
    const int quad = lane >> 4, l16 = lane & 15;
    // XCD swizzle: consecutive-resident blocks get consecutive (n,oh)
    const int lin = (blockIdx.x & 7) * 224 + (blockIdx.x >> 3);
    const int n = lin / HW, oh = lin % HW;

    // ---- stage: zero border columns (ow_lds = 0, 113) ----
    if (tid < 48) {
        const int r = tid >> 4, col = (tid >> 3) & 1, c8 = tid & 7;
        *(short8*)(xs + (r * 114 + col * 113) * TPITCH + c8 * 8) = (short8)0;
    }
    // ---- stage 3 rows (ih = oh-1 .. oh+1), 16B chunks, coalesced ----
    #pragma unroll
    for (int it = 0; it < 11; ++it) {
        const int g = it * 256 + tid;               // 2688 = 3 rows * 112 ow * 8 c8
        if (g < 2688) {
            const int r = g / 896, rem = g - r * 896;
            const int ow = rem >> 3, c8 = rem & 7;
            const int ih = oh - 1 + r;
            short8 v = (short8)0;
            if ((unsigned)ih < (unsigned)HW)
                v = *(const short8*)(xq + (((long)(n * HW + ih) * HW + ow) * C_IN) + c8 * 8);
            *(short8*)(xs + (r * 114 + ow + 1) * TPITCH + c8 * 8) = v;
        }
    }

    f32x4 acc[7][2];
    #pragma unroll
    for (int mt = 0; mt < 7; ++mt) { acc[mt][0] = (f32x4)0.f; acc[mt][1] = (f32x4)0.f; }

    // B-fragment pointers: wave owns channels [wave*32, wave*32+32)
    const unsigned short* wrow0 = wtp + (wave * 32 + l16) * K_TOT + quad * 8;
    const unsigned short* wrow1 = wrow0 + 16 * K_TOT;

    short8 bcur[2][2], bnxt[2][2];
    #pragma unroll
    for (int half = 0; half < 2; ++half) {
        bcur[half][0] = *(const short8*)(wrow0 + half * 32);
        bcur[half][1] = *(const short8*)(wrow1 + half * 32);
    }

    __syncthreads();

    #pragma unroll
    for (int tap = 0; tap < 9; ++tap) {
        if (tap < 8) {                              // prefetch next tap's B frags
            #pragma unroll
            for (int half = 0; half < 2; ++half) {
                bnxt[half][0] = *(const short8*)(wrow0 + (tap + 1) * C_IN + half * 32);
                bnxt[half][1] = *(const short8*)(wrow1 + (tap + 1) * C_IN + half * 32);
            }
        }
        const unsigned short* rowb = xs + (tap / 3) * (114 * TPITCH) + (tap % 3) * TPITCH + l16 * TPITCH + quad * 8;
        #pragma unroll
        for (int half = 0; half < 2; ++half) {
            #pragma unroll
            for (int mt = 0; mt < 7; ++mt) {
                const short8 afr = *(const short8*)(rowb + mt * (16 * TPITCH) + half * 32);
                acc[mt][0] = __builtin_amdgcn_mfma_f32_16x16x32_bf16(afr, bcur[half][0], acc[mt][0], 0, 0, 0);
                acc[mt][1] = __builtin_amdgcn_mfma_f32_16x16x32_bf16(afr, bcur[half][1], acc[mt][1], 0, 0, 0);
            }
        }
        #pragma unroll
        for (int half = 0; half < 2; ++half) {
            bcur[half][0] = bnxt[half][0];
            bcur[half][1] = bnxt[half][1];
        }
    }

    // ---- epilogue: dequant and store (4 consecutive ow per lane -> float4)
    const float s = fmaxf(__uint_as_float(scal[0]) * (1.f / 127.f), 1e-8f) *
                    fmaxf(__uint_as_float(scal[1]) * (1.f / 127.f), 1e-8f);
    #pragma unroll
    for (int mt = 0; mt < 7; ++mt) {
        #pragma unroll
        for (int ot = 0; ot < 2; ++ot) {
            const int o = wave * 32 + ot * 16 + l16;         // D col = lane&15
            const int mrow = mt * 16 + quad * 4;             // D row = quad*4 + reg
            const f32x4 v = acc[mt][ot] * s;
            *(f32x4*)(out + (((long)(n * O_CH + o) * HW + oh) * HW + mrow)) = v;
        }
    }
}

extern "C" void kernel_launch(void* const* d_in, const int* in_sizes, int n_in,
                              void* d_out, int out_size, void* d_ws, size_t ws_size,
                              hipStream_t stream) {
    const float* x = (const float*)d_in[0];
    const float* W = (const float*)d_in[1];
    float* out = (float*)d_out;

    unsigned* scal = (unsigned*)d_ws;                                    // 8 B
    __hip_bfloat16* wt = (__hip_bfloat16*)((char*)d_ws + 1024);          // 147,456 B
    unsigned short* xq = (unsigned short*)((char*)d_ws + 148480);        // 25,690,112 B
    // partials alias the head of xq: consumed by reduce_scal BEFORE quant_x writes xq
    float* part = (float*)xq;                                            // 2*NPART floats

    hipLaunchKernelGGL(absmax_part, dim3(NPART), dim3(256), 0, stream, x, W, part);
    hipLaunchKernelGGL(reduce_scal, dim3(1), dim3(256), 0, stream, part, scal);
    hipLaunchKernelGGL(quant_w, dim3(288), dim3(256), 0, stream, W, scal, wt);
    hipLaunchKernelGGL(quant_x, dim3(N_IMG * HW), dim3(256), 0, stream, x, scal, xq);
    hipLaunchKernelGGL(conv_kernel, dim3(N_IMG * HW), dim3(256), 0, stream, xq, (const unsigned short*)wt, scal, out);
}

// Round 6
// 171.365 us; speedup vs baseline: 2.2521x; 1.1599x over previous
//
#include <hip/hip_runtime.h>
#include <hip/hip_bf16.h>

// PCILT conv2d: qdq(x,8b) conv qdq(W,8b), 3x3 s1 p1.
// Path: pre-quantize x -> NHWC int8, W -> [o][tap*64+c] int8.
// Conv: one block per (n,oh); stage 3 padded int8 rows to LDS ONCE (one
// barrier), K-loop = 9 taps of ds_read_b128 + mfma_i32_16x16x64_i8 (exact
// integer math, i32 acc), B prefetched one tap ahead from global (L2-resident).
// Dequant in epilogue. Scales via atomic-free two-phase absmax reduction.

typedef __attribute__((ext_vector_type(8))) short short8;
typedef __attribute__((ext_vector_type(4))) int   int4v;    // 16 packed i8 (A/B) or i32 C/D
typedef __attribute__((ext_vector_type(4))) float f32x4;
typedef __attribute__((ext_vector_type(4))) float float4v;
typedef __attribute__((ext_vector_type(8)))  signed char char8;
typedef __attribute__((ext_vector_type(16))) signed char char16;

#define N_IMG 16
#define C_IN 64
#define HW 112
#define O_CH 128
#define WPITCH 576        // bytes per o-row in wt8 (9 taps * 64 c)
#define XPITCH 80         // LDS bytes per ow-row (64 + 16 pad: 8 words/bank both phases)
#define TP 72             // quant_x LDS pitch (halves)
#define NPART 3136        // absmax partial blocks (3136*256*4 float4 == nx4)

// ---------------- kernel 1: per-block absmax partials (NO atomics) ----------
__global__ __launch_bounds__(256) void absmax_part(const float* __restrict__ x,
                                                   const float* __restrict__ w,
                                                   float* __restrict__ part) {
    const int b = blockIdx.x, tid = threadIdx.x;
    const float4v* x4 = (const float4v*)x;
    const long base = (long)b * 1024 + tid;
    const float4v v0 = x4[base];
    const float4v v1 = x4[base + 256];
    const float4v v2 = x4[base + 512];
    const float4v v3 = x4[base + 768];
    float mx = fmaxf(fmaxf(fmaxf(fabsf(v0.x), fabsf(v0.y)), fmaxf(fabsf(v0.z), fabsf(v0.w))),
                     fmaxf(fmaxf(fabsf(v1.x), fabsf(v1.y)), fmaxf(fabsf(v1.z), fabsf(v1.w))));
    mx = fmaxf(mx, fmaxf(fmaxf(fabsf(v2.x), fabsf(v2.y)), fmaxf(fabsf(v2.z), fabsf(v2.w))));
    mx = fmaxf(mx, fmaxf(fmaxf(fabsf(v3.x), fabsf(v3.y)), fmaxf(fabsf(v3.z), fabsf(v3.w))));
    float mw = 0.f;
    if (b < 72) {   // 72*256 float4 == 73,728 W floats exactly
        const float4v q = ((const float4v*)w)[b * 256 + tid];
        mw = fmaxf(fmaxf(fabsf(q.x), fabsf(q.y)), fmaxf(fabsf(q.z), fabsf(q.w)));
    }
    #pragma unroll
    for (int off = 32; off > 0; off >>= 1) {
        mx = fmaxf(mx, __shfl_down(mx, off));
        mw = fmaxf(mw, __shfl_down(mw, off));
    }
    __shared__ float smx[4], smw[4];
    const int wave = tid >> 6, lane = tid & 63;
    if (lane == 0) { smx[wave] = mx; smw[wave] = mw; }
    __syncthreads();
    if (tid == 0) {
        part[b]         = fmaxf(fmaxf(smx[0], smx[1]), fmaxf(smx[2], smx[3]));
        part[NPART + b] = fmaxf(fmaxf(smw[0], smw[1]), fmaxf(smw[2], smw[3]));
    }
}

// ---------------- kernel 2: fold partials -> scal[0]=|x|max, scal[1]=|W|max --
__global__ __launch_bounds__(256) void reduce_scal(const float* __restrict__ part,
                                                   unsigned* __restrict__ scal) {
    const int tid = threadIdx.x;
    float mx = 0.f, mw = 0.f;
    for (int i = tid; i < NPART; i += 256) {
        mx = fmaxf(mx, part[i]);
        mw = fmaxf(mw, part[NPART + i]);
    }
    #pragma unroll
    for (int off = 32; off > 0; off >>= 1) {
        mx = fmaxf(mx, __shfl_down(mx, off));
        mw = fmaxf(mw, __shfl_down(mw, off));
    }
    __shared__ float smx[4], smw[4];
    const int wave = tid >> 6, lane = tid & 63;
    if (lane == 0) { smx[wave] = mx; smw[wave] = mw; }
    __syncthreads();
    if (tid == 0) {
        scal[0] = __float_as_uint(fmaxf(fmaxf(smx[0], smx[1]), fmaxf(smx[2], smx[3])));
        scal[1] = __float_as_uint(fmaxf(fmaxf(smw[0], smw[1]), fmaxf(smw[2], smw[3])));
    }
}

// -------- kernel 3: quantize W -> int8 wt8[o][(kh*3+kw)*64 + c] --------
__global__ __launch_bounds__(256) void quant_w(const float* __restrict__ w,
                                               const unsigned* __restrict__ scal,
                                               signed char* __restrict__ wt8) {
    const int idx = blockIdx.x * 256 + threadIdx.x;
    if (idx >= O_CH * C_IN * 9) return;
    const float sw = fmaxf(__uint_as_float(scal[1]) * (1.f / 127.f), 1e-8f);
    const int kw = idx % 3;
    int t = idx / 3;
    const int kh = t % 3;
    t /= 3;
    const int c = t % C_IN;
    const int o = t / C_IN;
    float v = rintf(w[idx] / sw);
    v = fminf(fmaxf(v, -127.f), 127.f);
    wt8[o * WPITCH + (kh * 3 + kw) * C_IN + c] = (signed char)(int)v;
}

// -------- kernel 4: quantize+transpose x -> xq NHWC int8 --------
// One block per (n,h); float4 reads along w, LDS transpose (XOR-swizzled
// c-octets), pack 16 int8 per lane, char16 writes along c.
__global__ __launch_bounds__(256) void quant_x(const float* __restrict__ x,
                                               const unsigned* __restrict__ scal,
                                               signed char* __restrict__ xq8) {
    __shared__ __align__(16) short tile[HW * TP];   // quantized ints as short, 16,128 B
    const int tid = threadIdx.x;
    const int n = blockIdx.x / HW, h = blockIdx.x % HW;
    const float inv_sx = 1.f / fmaxf(__uint_as_float(scal[0]) * (1.f / 127.f), 1e-8f);
    #pragma unroll
    for (int i = 0; i < 7; ++i) {                   // 7*256 = 1792 = 64c * 28 w-quads
        const int l = i * 256 + tid;
        const int c = l / 28, w4 = l - c * 28;
        const float4v v = *(const float4v*)(x + ((long)(n * C_IN + c) * HW + h) * HW + w4 * 4);
        float q[4];
        q[0] = fminf(fmaxf(rintf(v.x * inv_sx), -127.f), 127.f);
        q[1] = fminf(fmaxf(rintf(v.y * inv_sx), -127.f), 127.f);
        q[2] = fminf(fmaxf(rintf(v.z * inv_sx), -127.f), 127.f);
        q[3] = fminf(fmaxf(rintf(v.w * inv_sx), -127.f), 127.f);
        const int osw = ((c >> 3) ^ (w4 & 7)) * 8 + (c & 7);   // swizzled c position
        #pragma unroll
        for (int j = 0; j < 4; ++j)
            tile[(w4 * 4 + j) * TP + osw] = (short)q[j];
    }
    __syncthreads();
    const int g = tid & 3, wi = tid >> 2;           // 4 c-16-groups x 64 w-slots
    signed char* dst = xq8 + (long)(n * HW + h) * HW * C_IN;
    #pragma unroll
    for (int j = 0; j < 2; ++j) {
        const int w = j * 64 + wi;
        if (w < HW) {
            const int sw = (w >> 2) & 7;
            const short8 s0 = *(const short8*)(tile + w * TP + ((2 * g) ^ sw) * 8);
            const short8 s1 = *(const short8*)(tile + w * TP + ((2 * g + 1) ^ sw) * 8);
            const char8 c0 = __builtin_convertvector(s0, char8);
            const char8 c1 = __builtin_convertvector(s1, char8);
            const char16 cc = __builtin_shufflevector(c0, c1,
                0, 1, 2, 3, 4, 5, 6, 7, 8, 9, 10, 11, 12, 13, 14, 15);
            *(char16*)(dst + w * C_IN + g * 16) = cc;
        }
    }
}

// ---------------- kernel 5: conv — static-LDS int8 A, i8 MFMA ----------------
__global__ __launch_bounds__(256, 4) void conv_kernel(const signed char* __restrict__ xq8,
                                                      const signed char* __restrict__ wt8,
                                                      const unsigned* __restrict__ scal,
                                                      float* __restrict__ out) {
    __shared__ __align__(16) signed char xs[3 * 114 * XPITCH];   // 27,360 B
    const int tid = threadIdx.x;
    const int wave = tid >> 6, lane = tid & 63;
    const int quad = lane >> 4, l16 = lane & 15;
    // XCD swizzle: consecutive-resident blocks get consecutive (n,oh)
    const int lin = (blockIdx.x & 7) * 224 + (blockIdx.x >> 3);
    const int n = lin / HW, oh = lin % HW;

    // ---- zero border columns (ow_lds = 0, 113): 3 rows x 2 cols x 4 chunks
    if (tid < 24) {
        const int r = tid >> 3, col = (tid >> 2) & 1, c16 = tid & 3;
        *(int4v*)(xs + (r * 114 + col * 113) * XPITCH + c16 * 16) = (int4v)0;
    }
    // ---- stage 3 rows (ih = oh-1 .. oh+1), 16B chunks, coalesced ----
    #pragma unroll
    for (int it = 0; it < 6; ++it) {
        const int gph = it * 256 + tid;             // 1344 = 3 rows * 112 ow * 4 c16
        if (gph < 1344) {
            const int r = gph / 448, rem = gph - r * 448;
            const int ow = rem >> 2, c16 = rem & 3;
            const int ih = oh - 1 + r;
            int4v v = (int4v)0;
            if ((unsigned)ih < (unsigned)HW)
                v = *(const int4v*)(xq8 + ((long)(n * HW + ih) * HW + ow) * C_IN + c16 * 16);
            *(int4v*)(xs + (r * 114 + ow + 1) * XPITCH + c16 * 16) = v;
        }
    }

    int4v acc[7][2];
    #pragma unroll
    for (int mt = 0; mt < 7; ++mt) { acc[mt][0] = (int4v)0; acc[mt][1] = (int4v)0; }

    // B-fragment pointers: wave owns channels [wave*32, wave*32+32)
    const signed char* wrow0 = wt8 + (wave * 32 + l16) * WPITCH + quad * 16;
    const signed char* wrow1 = wrow0 + 16 * WPITCH;

    int4v bcur0 = *(const int4v*)(wrow0);
    int4v bcur1 = *(const int4v*)(wrow1);
    int4v bnxt0, bnxt1;

    __syncthreads();

    #pragma unroll
    for (int tap = 0; tap < 9; ++tap) {
        if (tap < 8) {                              // prefetch next tap's B frags
            bnxt0 = *(const int4v*)(wrow0 + (tap + 1) * C_IN);
            bnxt1 = *(const int4v*)(wrow1 + (tap + 1) * C_IN);
        }
        const signed char* rowb = xs + ((tap / 3) * 114 + (tap % 3) + l16) * XPITCH + quad * 16;
        #pragma unroll
        for (int mt = 0; mt < 7; ++mt) {
            const int4v afr = *(const int4v*)(rowb + mt * (16 * XPITCH));
            acc[mt][0] = __builtin_amdgcn_mfma_i32_16x16x64_i8(afr, bcur0, acc[mt][0], 0, 0, 0);
            acc[mt][1] = __builtin_amdgcn_mfma_i32_16x16x64_i8(afr, bcur1, acc[mt][1], 0, 0, 0);
        }
        bcur0 = bnxt0;
        bcur1 = bnxt1;
    }

    // ---- epilogue: dequant and store (4 consecutive ow per lane -> float4)
    const float s = fmaxf(__uint_as_float(scal[0]) * (1.f / 127.f), 1e-8f) *
                    fmaxf(__uint_as_float(scal[1]) * (1.f / 127.f), 1e-8f);
    #pragma unroll
    for (int mt = 0; mt < 7; ++mt) {
        #pragma unroll
        for (int ot = 0; ot < 2; ++ot) {
            const int o = wave * 32 + ot * 16 + l16;         // D col = lane&15
            const int mrow = mt * 16 + quad * 4;             // D row = quad*4 + reg
            const f32x4 v = __builtin_convertvector(acc[mt][ot], f32x4) * s;
            *(f32x4*)(out + (((long)(n * O_CH + o) * HW + oh) * HW + mrow)) = v;
        }
    }
}

extern "C" void kernel_launch(void* const* d_in, const int* in_sizes, int n_in,
                              void* d_out, int out_size, void* d_ws, size_t ws_size,
                              hipStream_t stream) {
    const float* x = (const float*)d_in[0];
    const float* W = (const float*)d_in[1];
    float* out = (float*)d_out;

    unsigned* scal = (unsigned*)d_ws;                                    // 8 B
    signed char* wt8 = (signed char*)((char*)d_ws + 1024);               // 73,728 B
    signed char* xq8 = (signed char*)((char*)d_ws + 76800);              // 12,845,056 B
    // partials alias the head of xq8: consumed by reduce_scal BEFORE quant_x writes
    float* part = (float*)xq8;                                           // 2*NPART floats

    hipLaunchKernelGGL(absmax_part, dim3(NPART), dim3(256), 0, stream, x, W, part);
    hipLaunchKernelGGL(reduce_scal, dim3(1), dim3(256), 0, stream, part, scal);
    hipLaunchKernelGGL(quant_w, dim3(288), dim3(256), 0, stream, W, scal, wt8);
    hipLaunchKernelGGL(quant_x, dim3(N_IMG * HW), dim3(256), 0, stream, x, scal, xq8);
    hipLaunchKernelGGL(conv_kernel, dim3(N_IMG * HW), dim3(256), 0, stream, xq8, wt8, scal, out);
}